// Round 1
// baseline (203.692 us; speedup 1.0000x reference)
//
#include <hip/hip_runtime.h>
#include <hip/hip_bf16.h>

// AugmentedTripletLoss on MI355X.
// inputs [8192,128] f32, targets [8192] int, center [16,128] f32 -> scalar loss.
//
// Pipeline:
//  1) prep_centers: L2-normalize the 16 prototypes; zero d_out.
//  2) prep_rows:    per row: sq=||x||^2 (fp32), bf16-convert x (row-major 256B/row),
//                   mindc = min_p ||x - cn_p|| (fp32 via sq + 1 - 2 x.cn).
//  3) pairdist:     bf16 MFMA Gram, streaming column tiles; per row track
//                   max/min of v = sq_j - 2*dot over same/diff-class masks.
//                   (sqrt is monotone -> defer sqrt to finalize.)
//  4) finalize:     merge strip partials, dist_ap/dist_an, center min, margin,
//                   block-reduce, atomicAdd mean into d_out[0].

#define N_ROWS 8192
#define DIM 128
#define NPROTO 16
#define MARGIN_F 1.0f
#define EPS_F 1e-12f

typedef __attribute__((ext_vector_type(8))) short short8;   // 8 bf16 = 4 VGPRs
typedef __attribute__((ext_vector_type(4))) float float4v;  // MFMA acc

static __device__ __forceinline__ unsigned short f2bf(float f) {
  // round-to-nearest-even bf16 (no NaN expected in this data)
  unsigned u = __float_as_uint(f);
  u += 0x7fffu + ((u >> 16) & 1u);
  return (unsigned short)(u >> 16);
}

__global__ void prep_centers_kernel(const float* __restrict__ center,
                                    float* __restrict__ cn,
                                    float* __restrict__ out0) {
  int tid = threadIdx.x;          // 256 threads: 16 rows x 16 lanes
  if (tid == 0) out0[0] = 0.0f;   // zero the loss accumulator (ordered on stream)
  int row = tid >> 4;
  int l = tid & 15;
  float v[8];
  float ss = 0.f;
#pragma unroll
  for (int j = 0; j < 8; ++j) {
    v[j] = center[row * DIM + l * 8 + j];
    ss += v[j] * v[j];
  }
  // 16-lane groups are contiguous within a wave -> xor masks 1..8 stay in-group
#pragma unroll
  for (int m = 1; m < 16; m <<= 1) ss += __shfl_xor(ss, m, 64);
  float inv = 1.0f / sqrtf(ss);
#pragma unroll
  for (int j = 0; j < 8; ++j) cn[row * DIM + l * 8 + j] = v[j] * inv;
}

__global__ void prep_rows_kernel(const float* __restrict__ x,
                                 const float* __restrict__ cn,
                                 unsigned int* __restrict__ xbf,
                                 float* __restrict__ sq,
                                 float* __restrict__ mindc) {
  __shared__ float scn[NPROTO * DIM];  // 8 KB
  int tid = threadIdx.x;
#pragma unroll
  for (int j = 0; j < 8; ++j) scn[j * 256 + tid] = cn[j * 256 + tid];
  __syncthreads();
  int wave = tid >> 6, lane = tid & 63;
  int row = blockIdx.x * 4 + wave;  // one row per wave
  float2 xv = ((const float2*)x)[row * 64 + lane];
  float s = xv.x * xv.x + xv.y * xv.y;
#pragma unroll
  for (int m = 1; m < 64; m <<= 1) s += __shfl_xor(s, m, 64);
  // bf16 pack: two bf16 per dword, row-major 256 B/row, coalesced
  xbf[row * 64 + lane] = (unsigned)f2bf(xv.x) | ((unsigned)f2bf(xv.y) << 16);
  // center distances in fp32: dc^2 = sq + 1 - 2 x.cn_p   (cn is unit-norm)
  float mind2 = INFINITY;
#pragma unroll
  for (int p = 0; p < NPROTO; ++p) {
    float d = xv.x * scn[p * DIM + 2 * lane] + xv.y * scn[p * DIM + 2 * lane + 1];
#pragma unroll
    for (int m = 1; m < 64; m <<= 1) d += __shfl_xor(d, m, 64);
    mind2 = fminf(mind2, s + 1.0f - 2.0f * d);
  }
  if (lane == 0) {
    sq[row] = s;
    mindc[row] = fmaxf(sqrtf(fmaxf(mind2, 0.0f)), EPS_F);
  }
}

// 512 blocks = 128 row-groups (M=64; wave w -> rows rg*64+w*16) x 4 column strips.
// Whole bf16 X (2 MB) fits per-XCD L2; B re-reads total 256 MB ~= 7.4 us at L2 BW.
__global__ __launch_bounds__(256, 2) void
pairdist_kernel(const char* __restrict__ xbf, const float* __restrict__ sq,
                const int* __restrict__ tgt, float* __restrict__ pmax,
                float* __restrict__ pmin) {
  int bid = blockIdx.x;
  int rg = bid >> 2;
  int strip = bid & 3;
  int wave = threadIdx.x >> 6, lane = threadIdx.x & 63;
  int rowbase = rg * 64 + wave * 16;
  int q = lane >> 4, l16 = lane & 15;

  // A-frag (16 rows x K=128): A[m=l16][k=q*8+j] per verified gfx950 layout.
  short8 a[4];
  {
    const char* ar = xbf + (size_t)(rowbase + l16) * 256 + q * 16;
#pragma unroll
    for (int kc = 0; kc < 4; ++kc) a[kc] = *(const short8*)(ar + kc * 64);
  }
  int trow[4];
#pragma unroll
  for (int r = 0; r < 4; ++r) trow[r] = tgt[rowbase + q * 4 + r];

  float maxp[4], minn[4];
#pragma unroll
  for (int r = 0; r < 4; ++r) { maxp[r] = -INFINITY; minn[r] = INFINITY; }

  int colstart = strip * 2048;
  for (int t = 0; t < 128; t += 2) {  // two independent 16-col tiles per iter (MFMA ILP)
    int c0 = colstart + t * 16;
    const char* br = xbf + (size_t)(c0 + l16) * 256 + q * 16;
    short8 b0[4], b1[4];
#pragma unroll
    for (int kc = 0; kc < 4; ++kc) b0[kc] = *(const short8*)(br + kc * 64);
#pragma unroll
    for (int kc = 0; kc < 4; ++kc) b1[kc] = *(const short8*)(br + 4096 + kc * 64);
    float sqc0 = sq[c0 + l16], sqc1 = sq[c0 + 16 + l16];
    int tc0 = tgt[c0 + l16], tc1 = tgt[c0 + 16 + l16];
    float4v acc0 = {0.f, 0.f, 0.f, 0.f}, acc1 = {0.f, 0.f, 0.f, 0.f};
#pragma unroll
    for (int kc = 0; kc < 4; ++kc)
      acc0 = __builtin_amdgcn_mfma_f32_16x16x32_bf16(a[kc], b0[kc], acc0, 0, 0, 0);
#pragma unroll
    for (int kc = 0; kc < 4; ++kc)
      acc1 = __builtin_amdgcn_mfma_f32_16x16x32_bf16(a[kc], b1[kc], acc1, 0, 0, 0);
    // C/D layout: col = lane&15, row = q*4 + reg (m89-verified)
#pragma unroll
    for (int r = 0; r < 4; ++r) {
      float v0 = fmaf(-2.0f, acc0[r], sqc0);  // dist2 = sq_row + v
      float v1 = fmaf(-2.0f, acc1[r], sqc1);
      bool s0 = (tc0 == trow[r]);
      bool s1 = (tc1 == trow[r]);
      maxp[r] = s0 ? fmaxf(maxp[r], v0) : maxp[r];
      minn[r] = s0 ? minn[r] : fminf(minn[r], v0);
      maxp[r] = s1 ? fmaxf(maxp[r], v1) : maxp[r];
      minn[r] = s1 ? minn[r] : fminf(minn[r], v1);
    }
  }
  // reduce across the 16 lanes of each quad (xor masks 1..8 stay in-group)
#pragma unroll
  for (int m = 1; m < 16; m <<= 1) {
#pragma unroll
    for (int r = 0; r < 4; ++r) {
      maxp[r] = fmaxf(maxp[r], __shfl_xor(maxp[r], m, 64));
      minn[r] = fminf(minn[r], __shfl_xor(minn[r], m, 64));
    }
  }
  if (l16 == 0) {
#pragma unroll
    for (int r = 0; r < 4; ++r) {
      int row = rowbase + q * 4 + r;
      pmax[strip * N_ROWS + row] = maxp[r];
      pmin[strip * N_ROWS + row] = minn[r];
    }
  }
}

__global__ void finalize_kernel(const float* __restrict__ pmax,
                                const float* __restrict__ pmin,
                                const float* __restrict__ sq,
                                const float* __restrict__ mindc,
                                float* __restrict__ out) {
  __shared__ float wsum[4];
  int i = blockIdx.x * 256 + threadIdx.x;  // 32 blocks x 256 = 8192 rows
  float maxv = -INFINITY, minv = INFINITY;
#pragma unroll
  for (int s = 0; s < 4; ++s) {
    maxv = fmaxf(maxv, pmax[s * N_ROWS + i]);
    minv = fminf(minv, pmin[s * N_ROWS + i]);
  }
  float si = sq[i];
  float dap = sqrtf(fmaxf(si + maxv, EPS_F));
  // no negative anywhere -> minv stays +inf -> dist_an = dist_ap + margin
  float dan = (minv > 1e37f) ? (dap + MARGIN_F) : sqrtf(fmaxf(si + minv, EPS_F));
  dan = fminf(dan, mindc[i]);
  float c = fmaxf(dap - dan + MARGIN_F, 0.0f) * (1.0f / (float)N_ROWS);
#pragma unroll
  for (int m = 1; m < 64; m <<= 1) c += __shfl_xor(c, m, 64);
  int lane = threadIdx.x & 63, wave = threadIdx.x >> 6;
  if (lane == 0) wsum[wave] = c;
  __syncthreads();
  if (threadIdx.x == 0) atomicAdd(out, wsum[0] + wsum[1] + wsum[2] + wsum[3]);
}

extern "C" void kernel_launch(void* const* d_in, const int* in_sizes, int n_in,
                              void* d_out, int out_size, void* d_ws, size_t ws_size,
                              hipStream_t stream) {
  const float* inputs = (const float*)d_in[0];
  const int* targets = (const int*)d_in[1];   // per harness: integer -> const int*
  const float* center = (const float*)d_in[2];
  char* ws = (char*)d_ws;
  // ws layout (all 256B-aligned):
  unsigned int* xbf = (unsigned int*)(ws + 0);        // 8192*256 B bf16 X   = 2 MB
  float* sq        = (float*)(ws + 2097152);          // 8192 f32            = 32 KB
  float* mindc     = (float*)(ws + 2129920);          // 8192 f32            = 32 KB
  float* cn        = (float*)(ws + 2162688);          // 16*128 f32          = 8 KB
  float* pmax      = (float*)(ws + 2170880);          // 4*8192 f32          = 128 KB
  float* pmin      = (float*)(ws + 2301952);          // 4*8192 f32          = 128 KB
  float* out       = (float*)d_out;

  prep_centers_kernel<<<1, 256, 0, stream>>>(center, cn, out);
  prep_rows_kernel<<<2048, 256, 0, stream>>>(inputs, cn, xbf, sq, mindc);
  pairdist_kernel<<<512, 256, 0, stream>>>((const char*)xbf, sq, targets, pmax, pmin);
  finalize_kernel<<<32, 256, 0, stream>>>(pmax, pmin, sq, mindc, out);
}

// Round 2
// 111.071 us; speedup vs baseline: 1.8339x; 1.8339x over previous
//
#include <hip/hip_runtime.h>
#include <hip/hip_bf16.h>

// AugmentedTripletLoss on MI355X.
// inputs [8192,128] f32, targets [8192] int, center [16,128] f32 -> scalar loss.
//
// v2: pairdist restructured. Old: 4 waves/block duplicated B reads (1 GB L2),
// 512 blocks (8 waves/CU), no prefetch -> latency-bound (MfmaUtil 4.9%).
// New: each wave holds A for all 64 block rows (4 row-tiles, 16 MFMA per
// B-tile) and waves partition the column strip (B read once per block,
// ~330 MB total L2 traffic), depth-1 B prefetch, 1024 blocks.

#define N_ROWS 8192
#define DIM 128
#define NPROTO 16
#define MARGIN_F 1.0f
#define EPS_F 1e-12f

typedef __attribute__((ext_vector_type(8))) short short8;   // 8 bf16 = 4 VGPRs
typedef __attribute__((ext_vector_type(4))) float float4v;  // MFMA acc

static __device__ __forceinline__ unsigned f2bf(float f) {
  // round-to-nearest-even bf16 (no NaN expected in this data)
  unsigned u = __float_as_uint(f);
  u += 0x7fffu + ((u >> 16) & 1u);
  return u >> 16;
}

__global__ void prep_centers_kernel(const float* __restrict__ center,
                                    float* __restrict__ cn,
                                    float* __restrict__ out0) {
  int tid = threadIdx.x;          // 256 threads: 16 rows x 16 lanes
  if (tid == 0) out0[0] = 0.0f;   // zero the loss accumulator (ordered on stream)
  int row = tid >> 4;
  int l = tid & 15;
  float v[8];
  float ss = 0.f;
#pragma unroll
  for (int j = 0; j < 8; ++j) {
    v[j] = center[row * DIM + l * 8 + j];
    ss += v[j] * v[j];
  }
  // 16-lane groups are contiguous within a wave -> xor masks 1..8 stay in-group
#pragma unroll
  for (int m = 1; m < 16; m <<= 1) ss += __shfl_xor(ss, m, 64);
  float inv = 1.0f / sqrtf(ss);
#pragma unroll
  for (int j = 0; j < 8; ++j) cn[row * DIM + l * 8 + j] = v[j] * inv;
}

// 16 rows per block: thread (r=tid>>4, l=tid&15) owns 8 contiguous dims.
__global__ void prep_rows_kernel(const float* __restrict__ x,
                                 const float* __restrict__ cn,
                                 uint4* __restrict__ xbf4,
                                 float* __restrict__ sq,
                                 float* __restrict__ mindc) {
  __shared__ float scn[NPROTO * DIM];  // 8 KB
  int tid = threadIdx.x;
#pragma unroll
  for (int j = 0; j < 8; ++j) scn[j * 256 + tid] = cn[j * 256 + tid];
  __syncthreads();
  int rloc = tid >> 4, l = tid & 15;
  int row = blockIdx.x * 16 + rloc;
  float4 v0 = ((const float4*)x)[row * 32 + l * 2];
  float4 v1 = ((const float4*)x)[row * 32 + l * 2 + 1];
  float ss = v0.x * v0.x + v0.y * v0.y + v0.z * v0.z + v0.w * v0.w +
             v1.x * v1.x + v1.y * v1.y + v1.z * v1.z + v1.w * v1.w;
  float dots[NPROTO];
#pragma unroll
  for (int p = 0; p < NPROTO; ++p) {
    const float* c = &scn[p * DIM + l * 8];
    dots[p] = v0.x * c[0] + v0.y * c[1] + v0.z * c[2] + v0.w * c[3] +
              v1.x * c[4] + v1.y * c[5] + v1.z * c[6] + v1.w * c[7];
  }
  // 16-lane reductions (xor masks 1..8 stay within the lane&15 group)
#pragma unroll
  for (int m = 1; m < 16; m <<= 1) {
    ss += __shfl_xor(ss, m, 64);
#pragma unroll
    for (int p = 0; p < NPROTO; ++p) dots[p] += __shfl_xor(dots[p], m, 64);
  }
  uint4 pk;
  pk.x = f2bf(v0.x) | (f2bf(v0.y) << 16);
  pk.y = f2bf(v0.z) | (f2bf(v0.w) << 16);
  pk.z = f2bf(v1.x) | (f2bf(v1.y) << 16);
  pk.w = f2bf(v1.z) | (f2bf(v1.w) << 16);
  xbf4[row * 16 + l] = pk;  // row-major bf16, 256 B/row, 16 B/lane coalesced
  if (l == 0) {
    float mind2 = INFINITY;
#pragma unroll
    for (int p = 0; p < NPROTO; ++p)
      mind2 = fminf(mind2, ss + 1.0f - 2.0f * dots[p]);  // cn is unit-norm
    sq[row] = ss;
    mindc[row] = fmaxf(sqrtf(fmaxf(mind2, 0.0f)), EPS_F);
  }
}

// Grid: 128 row-groups x 8 strips = 1024 blocks. Block = 4 waves; every wave
// holds A-frags for all 64 rows (4 row-tiles) and owns 256 columns (16 tiles)
// of the 1024-col strip. v = sq_j - 2*dot tracked (sqrt deferred: monotone).
__global__ __launch_bounds__(256, 2) void
pairdist_kernel(const char* __restrict__ xbf, const float* __restrict__ sq,
                const int* __restrict__ tgt, float* __restrict__ pmax,
                float* __restrict__ pmin) {
  __shared__ float smax[4][64];
  __shared__ float smin[4][64];
  int bid = blockIdx.x;
  int rg = bid >> 3;
  int strip = bid & 7;
  int wave = threadIdx.x >> 6, lane = threadIdx.x & 63;
  int rowbase = rg * 64;
  int q = lane >> 4, l16 = lane & 15;
  int colbase = strip * 1024 + wave * 256;

  // A-frags: A[m=l16][k=q*8+j] per verified gfx950 16x16x32 layout. 64 VGPRs.
  short8 a[4][4];
#pragma unroll
  for (int rt = 0; rt < 4; ++rt) {
    const char* ar = xbf + (size_t)(rowbase + rt * 16 + l16) * 256 + q * 16;
#pragma unroll
    for (int kc = 0; kc < 4; ++kc) a[rt][kc] = *(const short8*)(ar + kc * 64);
  }
  int4 trow[4];
#pragma unroll
  for (int rt = 0; rt < 4; ++rt)
    trow[rt] = ((const int4*)tgt)[(rowbase >> 2) + rt * 4 + q];

  float maxp[16], minn[16];
#pragma unroll
  for (int i = 0; i < 16; ++i) { maxp[i] = -INFINITY; minn[i] = INFINITY; }

  // depth-1 prefetch of B fragments + per-column sq/target
  short8 bn[4];
  float sqn;
  int tcn;
  {
    const char* br = xbf + (size_t)(colbase + l16) * 256 + q * 16;
#pragma unroll
    for (int kc = 0; kc < 4; ++kc) bn[kc] = *(const short8*)(br + kc * 64);
    sqn = sq[colbase + l16];
    tcn = tgt[colbase + l16];
  }

#pragma unroll
  for (int t = 0; t < 16; ++t) {
    short8 bc[4];
#pragma unroll
    for (int kc = 0; kc < 4; ++kc) bc[kc] = bn[kc];
    float sqc = sqn;
    int tc = tcn;
    int cnext = colbase + ((t + 1) & 15) * 16;  // wraps at t=15 (harmless reload)
    const char* br = xbf + (size_t)(cnext + l16) * 256 + q * 16;
#pragma unroll
    for (int kc = 0; kc < 4; ++kc) bn[kc] = *(const short8*)(br + kc * 64);
    sqn = sq[cnext + l16];
    tcn = tgt[cnext + l16];

    float4v acc[4];
#pragma unroll
    for (int rt = 0; rt < 4; ++rt) acc[rt] = (float4v){0.f, 0.f, 0.f, 0.f};
#pragma unroll
    for (int kc = 0; kc < 4; ++kc)
#pragma unroll
      for (int rt = 0; rt < 4; ++rt)  // 4 independent acc chains
        acc[rt] = __builtin_amdgcn_mfma_f32_16x16x32_bf16(a[rt][kc], bc[kc],
                                                          acc[rt], 0, 0, 0);
    // C/D layout: col = lane&15, row = q*4 + reg (m89-verified)
#pragma unroll
    for (int rt = 0; rt < 4; ++rt) {
      int tr[4] = {trow[rt].x, trow[rt].y, trow[rt].z, trow[rt].w};
#pragma unroll
      for (int r = 0; r < 4; ++r) {
        float v = fmaf(-2.0f, acc[rt][r], sqc);  // dist2 = sq_row + v
        bool s = (tc == tr[r]);
        int idx = rt * 4 + r;
        maxp[idx] = s ? fmaxf(maxp[idx], v) : maxp[idx];
        minn[idx] = s ? minn[idx] : fminf(minn[idx], v);
      }
    }
  }

  // reduce across the 16 lanes of each quad (xor masks 1..8 stay in-group)
#pragma unroll
  for (int m = 1; m < 16; m <<= 1) {
#pragma unroll
    for (int i = 0; i < 16; ++i) {
      maxp[i] = fmaxf(maxp[i], __shfl_xor(maxp[i], m, 64));
      minn[i] = fminf(minn[i], __shfl_xor(minn[i], m, 64));
    }
  }
  if (l16 == 0) {
#pragma unroll
    for (int rt = 0; rt < 4; ++rt)
#pragma unroll
      for (int r = 0; r < 4; ++r) {
        smax[wave][rt * 16 + q * 4 + r] = maxp[rt * 4 + r];
        smin[wave][rt * 16 + q * 4 + r] = minn[rt * 4 + r];
      }
  }
  __syncthreads();
  if (threadIdx.x < 64) {
    float M = fmaxf(fmaxf(smax[0][threadIdx.x], smax[1][threadIdx.x]),
                    fmaxf(smax[2][threadIdx.x], smax[3][threadIdx.x]));
    float m = fminf(fminf(smin[0][threadIdx.x], smin[1][threadIdx.x]),
                    fminf(smin[2][threadIdx.x], smin[3][threadIdx.x]));
    pmax[strip * N_ROWS + rowbase + threadIdx.x] = M;
    pmin[strip * N_ROWS + rowbase + threadIdx.x] = m;
  }
}

__global__ void finalize_kernel(const float* __restrict__ pmax,
                                const float* __restrict__ pmin,
                                const float* __restrict__ sq,
                                const float* __restrict__ mindc,
                                float* __restrict__ out) {
  __shared__ float wsum[4];
  int i = blockIdx.x * 256 + threadIdx.x;  // 32 blocks x 256 = 8192 rows
  float maxv = -INFINITY, minv = INFINITY;
#pragma unroll
  for (int s = 0; s < 8; ++s) {
    maxv = fmaxf(maxv, pmax[s * N_ROWS + i]);
    minv = fminf(minv, pmin[s * N_ROWS + i]);
  }
  float si = sq[i];
  float dap = sqrtf(fmaxf(si + maxv, EPS_F));
  // if no negative exists anywhere, minv stays +inf -> dist_an = dist_ap + margin
  float dan = (minv > 1e37f) ? (dap + MARGIN_F) : sqrtf(fmaxf(si + minv, EPS_F));
  dan = fminf(dan, mindc[i]);
  float c = fmaxf(dap - dan + MARGIN_F, 0.0f) * (1.0f / (float)N_ROWS);
#pragma unroll
  for (int m = 1; m < 64; m <<= 1) c += __shfl_xor(c, m, 64);
  int lane = threadIdx.x & 63, wave = threadIdx.x >> 6;
  if (lane == 0) wsum[wave] = c;
  __syncthreads();
  if (threadIdx.x == 0) atomicAdd(out, wsum[0] + wsum[1] + wsum[2] + wsum[3]);
}

extern "C" void kernel_launch(void* const* d_in, const int* in_sizes, int n_in,
                              void* d_out, int out_size, void* d_ws, size_t ws_size,
                              hipStream_t stream) {
  const float* inputs = (const float*)d_in[0];
  const int* targets = (const int*)d_in[1];   // per harness: integer -> const int*
  const float* center = (const float*)d_in[2];
  char* ws = (char*)d_ws;
  // ws layout (all 256B-aligned):
  uint4* xbf4     = (uint4*)(ws + 0);            // 8192*256 B bf16 X = 2 MB
  float* sq       = (float*)(ws + 2097152);      // 8192 f32  = 32 KB
  float* mindc    = (float*)(ws + 2129920);      // 8192 f32  = 32 KB
  float* cn       = (float*)(ws + 2162688);      // 16*128 f32 = 8 KB
  float* pmax     = (float*)(ws + 2170880);      // 8*8192 f32 = 256 KB
  float* pmin     = (float*)(ws + 2433024);      // 8*8192 f32 = 256 KB
  float* out      = (float*)d_out;

  prep_centers_kernel<<<1, 256, 0, stream>>>(center, cn, out);
  prep_rows_kernel<<<512, 256, 0, stream>>>(inputs, cn, xbf4, sq, mindc);
  pairdist_kernel<<<1024, 256, 0, stream>>>((const char*)xbf4, sq, targets, pmax, pmin);
  finalize_kernel<<<32, 256, 0, stream>>>(pmax, pmin, sq, mindc, out);
}